// Round 7
// baseline (211.550 us; speedup 1.0000x reference)
//
#include <hip/hip_runtime.h>
#include <cstddef>

#define NH 16
#define NKV 4
#define HD 128
#define SEQ 1024
#define SCALE_F 0.08838834764831845f
// SCALE * log2(e): QK^T logits come out pre-multiplied by log2(e), so
// softmax uses v_exp_f32 (exp2) directly -- saves one v_mul per exp.
#define QSCALE 0.12751743f

typedef __attribute__((ext_vector_type(8))) short short8;
typedef __attribute__((ext_vector_type(4))) float floatx4;

union F8 { short8 v; unsigned short u[8]; };

__device__ __forceinline__ unsigned short f2bf(float f) {
  unsigned int u = __float_as_uint(f);
  u += 0x7FFFu + ((u >> 16) & 1u);
  return (unsigned short)(u >> 16);
}

__device__ __forceinline__ unsigned int pk_bf16(float lo, float hi) {
  unsigned int r;
  asm("v_cvt_pk_bf16_f32 %0, %1, %2" : "=v"(r) : "v"(lo), "v"(hi));
  return r;
}

__device__ __forceinline__ void glds16(const void* g, void* l) {
  __builtin_amdgcn_global_load_lds(
      (const __attribute__((address_space(1))) unsigned int*)g,
      (__attribute__((address_space(3))) unsigned int*)l, 16, 0, 0);
}

// ---------------------------------------------------------------------------
// Pre-pass (unchanged, verified): K -> bf16 tiled+swizzled [512][32 kpos][16],
// blk' = kpos*16 + (d8 ^ (kpos&15)); V -> bf16 transposed [512][128 d][4]
// with k-interleave perm s=2*(k&15)+(k>>4) and blk' = d*4 + (s8 ^ (d&3)).
// ---------------------------------------------------------------------------
__global__ __launch_bounds__(256) void prepass(const float* __restrict__ kg,
                                               const float* __restrict__ vg,
                                               unsigned short* __restrict__ Ktg,
                                               unsigned short* __restrict__ Vtg) {
  __shared__ float Vl[32 * 132];
  const int tid = threadIdx.x;
  const int bid = blockIdx.x;
  if (bid < 512) {
    const int bkvh = bid >> 5, tile = bid & 31;
    const int b = bkvh >> 2, kvh = bkvh & 3;
    const int kpos = tid >> 3;
    const int d8base = (tid & 7) * 2;
    const size_t tok = (size_t)b * SEQ + tile * 32 + kpos;
    const float* src = kg + (tok * NKV + kvh) * HD + d8base * 8;
    unsigned short* dstT = Ktg + (size_t)bid * 4096;
#pragma unroll
    for (int i = 0; i < 2; ++i) {
      floatx4 a = ((const floatx4*)src)[0];
      floatx4 c = ((const floatx4*)src)[1];
      F8 t;
#pragma unroll
      for (int j = 0; j < 4; ++j) { t.u[j] = f2bf(a[j]); t.u[4 + j] = f2bf(c[j]); }
      const int blk = kpos * 16 + ((d8base + i) ^ (kpos & 15));
      *(short8*)(dstT + blk * 8) = t.v;
      src += 8;
    }
  } else {
    const int bb = bid - 512;
    const int bkvh = bb >> 5, tile = bb & 31;
    const int b = bkvh >> 2, kvh = bkvh & 3;
    const int r = tid >> 3;
    const int c16 = (tid & 7) * 16;
    const size_t tok = (size_t)b * SEQ + tile * 32 + r;
    const float* src = vg + (tok * NKV + kvh) * HD + c16;
#pragma unroll
    for (int j = 0; j < 4; ++j)
      *(floatx4*)&Vl[r * 132 + c16 + j * 4] = ((const floatx4*)src)[j];
    __syncthreads();
    unsigned short* dstT = Vtg + (size_t)bb * 4096;
#pragma unroll
    for (int i = 0; i < 2; ++i) {
      const int o = tid * 2 + i;
      const int d = o >> 2, s8 = o & 3;
      F8 t;
#pragma unroll
      for (int j = 0; j < 8; ++j) {
        const int s = s8 * 8 + j;
        const int k = (s >> 1) + ((s & 1) << 4);  // interleave perm (matches P pack)
        t.u[j] = f2bf(Vl[k * 132 + d]);
      }
      const int blk = d * 4 + (s8 ^ (d & 3));
      *(short8*)(dstT + blk * 8) = t.v;
    }
  }
}

// ---------------------------------------------------------------------------
// Hot kernel v8 = R6-verified per-tile compute, restructured to a 64-row
// K-step: TWO 32-row tiles per barrier (halves the barrier count 32->16 for
// the critical block; per-iteration compute ~2x now dominates the fixed
// latency chain). Both halves' V fragments load at the TOP, before the
// K-DMA issue (vmcnt FIFO: PV0 waits at vmcnt(12), PV1 at vmcnt(4) -- the
// K prefetch never drains mid-iteration). nkt = 2*(qt+1) is always even.
// Per-tile arithmetic is verbatim R6 -> output bit-identical.
// ---------------------------------------------------------------------------
__global__ __launch_bounds__(256, 4)
void fa_fwd8(const float* __restrict__ qg, const unsigned short* __restrict__ Ktg,
             const unsigned short* __restrict__ Vtg, float* __restrict__ og) {
  __shared__ __align__(16) unsigned short Kb[2][2][4096];  // [buf][half][tile] 32KB
  __shared__ __align__(16) unsigned int Pb[4][16 * 20];    // 5KB, stride 20 dw

  const int tid = threadIdx.x;
  const int wave = tid >> 6;
  const int lane = tid & 63;
  const int col = lane & 15;
  const int quad = lane >> 4;

  const int idx = blockIdx.x;
  // Co-resident blocks {i, i+256, i+512, i+768} get qt = g*4 + ((u+g)&3):
  // bijective over (g,u) per bh, and sum of qt over g is 30 for every u.
  const int g = idx >> 8;
  const int u = (idx >> 6) & 3;
  const int bh = idx & 63;
  const int qt = g * 4 + ((u + g) & 3);
  const int h = bh & 15;
  const int b = bh >> 4;
  const int kvh = h >> 2;
  const int seg = b * SEQ;
  const int wq0 = qt * 64 + wave * 16;
  const int tb = (b * NKV + kvh) * 32;  // global tile index base

  // Q A-fragment [m=col][k=quad*8+j], pre-scaled bf16 (scale*log2e folded)
  F8 qf[4];
  {
    const float* qp = qg + ((size_t)(seg + wq0 + col) * NH + h) * HD + quad * 8;
#pragma unroll
    for (int ks = 0; ks < 4; ++ks) {
      floatx4 a = ((const floatx4*)(qp + ks * 32))[0];
      floatx4 c = ((const floatx4*)(qp + ks * 32))[1];
#pragma unroll
      for (int j = 0; j < 4; ++j) {
        qf[ks].u[j] = f2bf(a[j] * QSCALE);
        qf[ks].u[4 + j] = f2bf(c[j] * QSCALE);
      }
    }
  }

  floatx4 acc[8];
#pragma unroll
  for (int dt = 0; dt < 8; ++dt) acc[dt] = (floatx4){0.f, 0.f, 0.f, 0.f};
  float lsum[4] = {0.f, 0.f, 0.f, 0.f};

  const int nkt = 2 * (qt + 1);  // even
  const int stoff = wave * 2048 + lane * 16;  // byte offset in 8KB tile

  // Stage the K tile PAIR (T, T+1) into Kb[BUF][0..1]; 4 glds16 per wave.
#define STAGE2(T, BUF)                                                      \
  do {                                                                      \
    const size_t go_ = (size_t)(tb + (T)) * 8192 + stoff;                   \
    char* lK0_ = (char*)&Kb[BUF][0][0] + wave * 2048;                       \
    glds16((const char*)Ktg + go_, lK0_);                                   \
    glds16((const char*)Ktg + go_ + 1024, lK0_ + 1024);                     \
    char* lK1_ = (char*)&Kb[BUF][1][0] + wave * 2048;                       \
    glds16((const char*)Ktg + go_ + 8192, lK1_);                            \
    glds16((const char*)Ktg + go_ + 8192 + 1024, lK1_ + 1024);              \
  } while (0)

  // Prologue: DMA tile pair (0,1) into buffer 0 (nkt >= 2 always)
  STAGE2(0, 0);
  __syncthreads();

  for (int kt = 0; kt < nkt; kt += 2) {
    const int cb = (kt >> 1) & 1, nb = cb ^ 1;
    const int kb0 = kt * 32;
    const int kb1 = kb0 + 32;
    const bool act0 = (kb0 <= wq0 + 15);  // act1 implies act0
    const bool act1 = (kb1 <= wq0 + 15);

    // ---- (1) V fragments for BOTH halves: issue first (oldest in vmcnt) ----
    F8 vr0[8], vr1[8];
    if (act0) {
      const unsigned short* Vt = Vtg + (size_t)(tb + kt) * 4096;
#pragma unroll
      for (int dt = 0; dt < 8; ++dt)
        vr0[dt].v = *(const short8*)&Vt[((dt * 16 + col) * 4 + (quad ^ (col & 3))) * 8];
    }
    if (act1) {
      const unsigned short* Vt = Vtg + (size_t)(tb + kt + 1) * 4096;
#pragma unroll
      for (int dt = 0; dt < 8; ++dt)
        vr1[dt].v = *(const short8*)&Vt[((dt * 16 + col) * 4 + (quad ^ (col & 3))) * 8];
    }

    // ---- (2) prefetch next K tile pair (drained by this iter's barrier) ----
    if (kt + 2 < nkt) STAGE2(kt + 2, nb);

    // ---- half 0: tile kt ----
    if (act0) {
      floatx4 s0 = {0.f, 0.f, 0.f, 0.f}, s1 = {0.f, 0.f, 0.f, 0.f};
#pragma unroll
      for (int ks = 0; ks < 4; ++ks) {
        F8 k0, k1;
        k0.v = *(const short8*)&Kb[cb][0][(col * 16 + ((ks * 4 + quad) ^ col)) * 8];
        k1.v = *(const short8*)&Kb[cb][0][((16 + col) * 16 + ((ks * 4 + quad) ^ col)) * 8];
        s0 = __builtin_amdgcn_mfma_f32_16x16x32_bf16(qf[ks].v, k0.v, s0, 0, 0, 0);
        s1 = __builtin_amdgcn_mfma_f32_16x16x32_bf16(qf[ks].v, k1.v, s1, 0, 0, 0);
      }
      const bool diag = (kb0 + 31 > wq0);
#pragma unroll
      for (int r = 0; r < 4; ++r) {
        float p0 = __builtin_amdgcn_exp2f(s0[r]);
        float p1 = __builtin_amdgcn_exp2f(s1[r]);
        if (diag) {
          const int q0 = wq0 + quad * 4 + r;
          p0 = (kb0 + col > q0) ? 0.f : p0;
          p1 = (kb0 + 16 + col > q0) ? 0.f : p1;
        }
        lsum[r] += p0 + p1;
        Pb[wave][(quad * 4 + r) * 20 + col] = pk_bf16(p0, p1);
      }
      F8 pa;
      pa.v = *(const short8*)&Pb[wave][col * 20 + quad * 4];
#pragma unroll
      for (int dt = 0; dt < 8; ++dt)
        acc[dt] = __builtin_amdgcn_mfma_f32_16x16x32_bf16(pa.v, vr0[dt].v, acc[dt], 0, 0, 0);
    }

    // ---- half 1: tile kt+1 ----
    if (act1) {
      floatx4 s0 = {0.f, 0.f, 0.f, 0.f}, s1 = {0.f, 0.f, 0.f, 0.f};
#pragma unroll
      for (int ks = 0; ks < 4; ++ks) {
        F8 k0, k1;
        k0.v = *(const short8*)&Kb[cb][1][(col * 16 + ((ks * 4 + quad) ^ col)) * 8];
        k1.v = *(const short8*)&Kb[cb][1][((16 + col) * 16 + ((ks * 4 + quad) ^ col)) * 8];
        s0 = __builtin_amdgcn_mfma_f32_16x16x32_bf16(qf[ks].v, k0.v, s0, 0, 0, 0);
        s1 = __builtin_amdgcn_mfma_f32_16x16x32_bf16(qf[ks].v, k1.v, s1, 0, 0, 0);
      }
      const bool diag = (kb1 + 31 > wq0);
#pragma unroll
      for (int r = 0; r < 4; ++r) {
        float p0 = __builtin_amdgcn_exp2f(s0[r]);
        float p1 = __builtin_amdgcn_exp2f(s1[r]);
        if (diag) {
          const int q0 = wq0 + quad * 4 + r;
          p0 = (kb1 + col > q0) ? 0.f : p0;
          p1 = (kb1 + 16 + col > q0) ? 0.f : p1;
        }
        lsum[r] += p0 + p1;
        Pb[wave][(quad * 4 + r) * 20 + col] = pk_bf16(p0, p1);
      }
      F8 pa;
      pa.v = *(const short8*)&Pb[wave][col * 20 + quad * 4];
#pragma unroll
      for (int dt = 0; dt < 8; ++dt)
        acc[dt] = __builtin_amdgcn_mfma_f32_16x16x32_bf16(pa.v, vr1[dt].v, acc[dt], 0, 0, 0);
    }
    __syncthreads();
  }
#undef STAGE2

  // ---- epilogue: reduce row sums, normalize, store ----
#pragma unroll
  for (int r = 0; r < 4; ++r) {
    float l = lsum[r];
    l += __shfl_xor(l, 1);
    l += __shfl_xor(l, 2);
    l += __shfl_xor(l, 4);
    l += __shfl_xor(l, 8);
    const float inv = 1.0f / l;
    float* op = og + ((size_t)(seg + wq0 + quad * 4 + r) * NH + h) * HD;
#pragma unroll
    for (int dt = 0; dt < 8; ++dt) op[dt * 16 + col] = acc[dt][r] * inv;
  }
}

// ---------------------------------------------------------------------------
// Fallback (R2 kernel) if d_ws is too small for the pre-pass buffers.
// ---------------------------------------------------------------------------
#define KST 136
#define VST 40
#define PST 40

__global__ __launch_bounds__(256, 2)
void fa_fwd(const float* __restrict__ qg, const float* __restrict__ kg,
            const float* __restrict__ vg, float* __restrict__ og) {
  __shared__ unsigned short Klds[32 * KST];
  __shared__ unsigned short Vt[HD * VST];
  __shared__ unsigned short Pl[4][32 * PST];

  const int tid = threadIdx.x;
  const int wave = tid >> 6;
  const int lane = tid & 63;
  const int col = lane & 15;
  const int quad = lane >> 4;

  const int idx = blockIdx.x;
  const int raw = idx & 7;
  const int qt = (idx & 256) ? raw : 7 - raw;
  const int bh = idx >> 3;
  const int h = bh & 15;
  const int b = bh >> 4;
  const int kvh = h >> 2;
  const int seg = b * SEQ;
  const int wq0 = qt * 128 + wave * 32;

  F8 qf[2][4];
#pragma unroll
  for (int mt = 0; mt < 2; ++mt) {
    const size_t qrow = (size_t)(seg + wq0 + mt * 16 + col);
    const float* qp = qg + (qrow * NH + h) * HD + quad * 8;
#pragma unroll
    for (int ks = 0; ks < 4; ++ks) {
      const floatx4* p4 = (const floatx4*)(qp + ks * 32);
      floatx4 a = p4[0], c = p4[1];
#pragma unroll
      for (int j = 0; j < 4; ++j) {
        qf[mt][ks].u[j] = f2bf(a[j] * SCALE_F);
        qf[mt][ks].u[4 + j] = f2bf(c[j] * SCALE_F);
      }
    }
  }

  floatx4 acc[2][8];
#pragma unroll
  for (int mt = 0; mt < 2; ++mt)
#pragma unroll
    for (int dt = 0; dt < 8; ++dt)
      acc[mt][dt] = (floatx4){0.f, 0.f, 0.f, 0.f};
  float lsum[2][4];
#pragma unroll
  for (int mt = 0; mt < 2; ++mt)
#pragma unroll
    for (int r = 0; r < 4; ++r) lsum[mt][r] = 0.f;

  const int nkt = 4 * (qt + 1);
  const int sr = tid >> 3;
  const int sc = (tid & 7) * 16;

  for (int kt = 0; kt < nkt; ++kt) {
    const int kbase = kt * 32;
    __syncthreads();
    {
      const size_t tok = (size_t)(seg + kbase + sr);
      const floatx4* kp4 = (const floatx4*)(kg + (tok * NKV + kvh) * HD + sc);
      floatx4 kv0 = kp4[0], kv1 = kp4[1], kv2 = kp4[2], kv3 = kp4[3];
      float kf32[16] = {kv0[0],kv0[1],kv0[2],kv0[3], kv1[0],kv1[1],kv1[2],kv1[3],
                        kv2[0],kv2[1],kv2[2],kv2[3], kv3[0],kv3[1],kv3[2],kv3[3]};
      unsigned int* dst = (unsigned int*)&Klds[sr * KST + sc];
#pragma unroll
      for (int j = 0; j < 8; ++j)
        dst[j] = (unsigned int)f2bf(kf32[2 * j]) | ((unsigned int)f2bf(kf32[2 * j + 1]) << 16);
      const floatx4* vp4 = (const floatx4*)(vg + (tok * NKV + kvh) * HD + sc);
      floatx4 vv0 = vp4[0], vv1 = vp4[1], vv2 = vp4[2], vv3 = vp4[3];
      unsigned short vb[16] = {
        f2bf(vv0[0]),f2bf(vv0[1]),f2bf(vv0[2]),f2bf(vv0[3]),
        f2bf(vv1[0]),f2bf(vv1[1]),f2bf(vv1[2]),f2bf(vv1[3]),
        f2bf(vv2[0]),f2bf(vv2[1]),f2bf(vv2[2]),f2bf(vv2[3]),
        f2bf(vv3[0]),f2bf(vv3[1]),f2bf(vv3[2]),f2bf(vv3[3])};
#pragma unroll
      for (int s = 0; s < 16; ++s) {
        int j = (s + tid) & 15;
        Vt[(sc + j) * VST + sr] = vb[j];
      }
    }
    __syncthreads();

    if (kbase > wq0 + 31) continue;

    F8 kf[4][2];
#pragma unroll
    for (int ks = 0; ks < 4; ++ks)
#pragma unroll
      for (int nt = 0; nt < 2; ++nt)
        kf[ks][nt].v = *(const short8*)&Klds[(nt * 16 + col) * KST + ks * 32 + quad * 8];

#pragma unroll
    for (int mt = 0; mt < 2; ++mt) {
      floatx4 s0 = {0.f, 0.f, 0.f, 0.f}, s1 = {0.f, 0.f, 0.f, 0.f};
#pragma unroll
      for (int ks = 0; ks < 4; ++ks) {
        s0 = __builtin_amdgcn_mfma_f32_16x16x32_bf16(qf[mt][ks].v, kf[ks][0].v, s0, 0, 0, 0);
        s1 = __builtin_amdgcn_mfma_f32_16x16x32_bf16(qf[mt][ks].v, kf[ks][1].v, s1, 0, 0, 0);
      }
      const int q0 = wq0 + mt * 16 + quad * 4;
      const bool diag = (kbase + 31 > wq0 + mt * 16);
      unsigned short* pw = &Pl[wave][(mt * 16 + quad * 4) * PST];
#pragma unroll
      for (int r = 0; r < 4; ++r) {
        float p0 = __expf(s0[r]);
        float p1 = __expf(s1[r]);
        if (diag) {
          p0 = (kbase + col > q0 + r) ? 0.f : p0;
          p1 = (kbase + 16 + col > q0 + r) ? 0.f : p1;
        }
        lsum[mt][r] += p0 + p1;
        pw[r * PST + col] = f2bf(p0);
        pw[r * PST + 16 + col] = f2bf(p1);
      }
    }
    F8 pa[2];
#pragma unroll
    for (int mt = 0; mt < 2; ++mt)
      pa[mt].v = *(const short8*)&Pl[wave][(mt * 16 + col) * PST + quad * 8];
#pragma unroll
    for (int dt = 0; dt < 8; ++dt) {
      F8 vb;
      vb.v = *(const short8*)&Vt[(dt * 16 + col) * VST + quad * 8];
#pragma unroll
      for (int mt = 0; mt < 2; ++mt)
        acc[mt][dt] = __builtin_amdgcn_mfma_f32_16x16x32_bf16(pa[mt].v, vb.v, acc[mt][dt], 0, 0, 0);
    }
  }

#pragma unroll
  for (int mt = 0; mt < 2; ++mt) {
#pragma unroll
    for (int r = 0; r < 4; ++r) {
      float l = lsum[mt][r];
      l += __shfl_xor(l, 1);
      l += __shfl_xor(l, 2);
      l += __shfl_xor(l, 4);
      l += __shfl_xor(l, 8);
      const float inv = 1.0f / l;
      const int qi = wq0 + mt * 16 + quad * 4 + r;
      float* op = og + ((size_t)(seg + qi) * NH + h) * HD;
#pragma unroll
      for (int dt = 0; dt < 8; ++dt)
        op[dt * 16 + col] = acc[mt][dt][r] * inv;
    }
  }
}

extern "C" void kernel_launch(void* const* d_in, const int* in_sizes, int n_in,
                              void* d_out, int out_size, void* d_ws, size_t ws_size,
                              hipStream_t stream) {
  const float* q = (const float*)d_in[0];
  const float* k = (const float*)d_in[1];
  const float* v = (const float*)d_in[2];
  float* out = (float*)d_out;
  if (ws_size >= (size_t)(8 * 1024 * 1024)) {
    unsigned short* Ktg = (unsigned short*)d_ws;
    unsigned short* Vtg = Ktg + 2097152;  // +4MB
    hipLaunchKernelGGL(prepass, dim3(1024), dim3(256), 0, stream, k, v, Ktg, Vtg);
    hipLaunchKernelGGL(fa_fwd8, dim3(1024), dim3(256), 0, stream, q, Ktg, Vtg, out);
  } else {
    hipLaunchKernelGGL(fa_fwd, dim3(512), dim3(256), 0, stream, q, k, v, out);
  }
}

// Round 8
// 139.819 us; speedup vs baseline: 1.5130x; 1.5130x over previous
//
#include <hip/hip_runtime.h>
#include <cstddef>

#define NH 16
#define NKV 4
#define HD 128
#define SEQ 1024
#define SCALE_F 0.08838834764831845f
// SCALE * log2(e): QK^T logits come out pre-multiplied by log2(e), so
// softmax uses v_exp_f32 (exp2) directly -- saves one v_mul per exp.
#define QSCALE 0.12751743f

typedef __attribute__((ext_vector_type(8))) short short8;
typedef __attribute__((ext_vector_type(4))) float floatx4;

union F8 { short8 v; unsigned short u[8]; };

__device__ __forceinline__ unsigned short f2bf(float f) {
  unsigned int u = __float_as_uint(f);
  u += 0x7FFFu + ((u >> 16) & 1u);
  return (unsigned short)(u >> 16);
}

__device__ __forceinline__ unsigned int pk_bf16(float lo, float hi) {
  unsigned int r;
  asm("v_cvt_pk_bf16_f32 %0, %1, %2" : "=v"(r) : "v"(lo), "v"(hi));
  return r;
}

__device__ __forceinline__ void glds16(const void* g, void* l) {
  __builtin_amdgcn_global_load_lds(
      (const __attribute__((address_space(1))) unsigned int*)g,
      (__attribute__((address_space(3))) unsigned int*)l, 16, 0, 0);
}

// ---------------------------------------------------------------------------
// Pre-pass (unchanged, verified): K -> bf16 tiled+swizzled [512][32 kpos][16],
// blk' = kpos*16 + (d8 ^ (kpos&15)); V -> bf16 transposed [512][128 d][4]
// with k-interleave perm s=2*(k&15)+(k>>4) and blk' = d*4 + (s8 ^ (d&3)).
// ---------------------------------------------------------------------------
__global__ __launch_bounds__(256) void prepass(const float* __restrict__ kg,
                                               const float* __restrict__ vg,
                                               unsigned short* __restrict__ Ktg,
                                               unsigned short* __restrict__ Vtg) {
  __shared__ float Vl[32 * 132];
  const int tid = threadIdx.x;
  const int bid = blockIdx.x;
  if (bid < 512) {
    const int bkvh = bid >> 5, tile = bid & 31;
    const int b = bkvh >> 2, kvh = bkvh & 3;
    const int kpos = tid >> 3;
    const int d8base = (tid & 7) * 2;
    const size_t tok = (size_t)b * SEQ + tile * 32 + kpos;
    const float* src = kg + (tok * NKV + kvh) * HD + d8base * 8;
    unsigned short* dstT = Ktg + (size_t)bid * 4096;
#pragma unroll
    for (int i = 0; i < 2; ++i) {
      floatx4 a = ((const floatx4*)src)[0];
      floatx4 c = ((const floatx4*)src)[1];
      F8 t;
#pragma unroll
      for (int j = 0; j < 4; ++j) { t.u[j] = f2bf(a[j]); t.u[4 + j] = f2bf(c[j]); }
      const int blk = kpos * 16 + ((d8base + i) ^ (kpos & 15));
      *(short8*)(dstT + blk * 8) = t.v;
      src += 8;
    }
  } else {
    const int bb = bid - 512;
    const int bkvh = bb >> 5, tile = bb & 31;
    const int b = bkvh >> 2, kvh = bkvh & 3;
    const int r = tid >> 3;
    const int c16 = (tid & 7) * 16;
    const size_t tok = (size_t)b * SEQ + tile * 32 + r;
    const float* src = vg + (tok * NKV + kvh) * HD + c16;
#pragma unroll
    for (int j = 0; j < 4; ++j)
      *(floatx4*)&Vl[r * 132 + c16 + j * 4] = ((const floatx4*)src)[j];
    __syncthreads();
    unsigned short* dstT = Vtg + (size_t)bb * 4096;
#pragma unroll
    for (int i = 0; i < 2; ++i) {
      const int o = tid * 2 + i;
      const int d = o >> 2, s8 = o & 3;
      F8 t;
#pragma unroll
      for (int j = 0; j < 8; ++j) {
        const int s = s8 * 8 + j;
        const int k = (s >> 1) + ((s & 1) << 4);  // interleave perm (matches P pack)
        t.u[j] = f2bf(Vl[k * 132 + d]);
      }
      const int blk = d * 4 + (s8 ^ (d & 3));
      *(short8*)(dstT + blk * 8) = t.v;
    }
  }
}

// ---------------------------------------------------------------------------
// Hot kernel v9: SPLIT-K over the causal triangle. Max-free softmax makes
// partial (acc, lsum) over disjoint K-ranges exactly additive, so:
//   qt 0..7  -> one block, full range [0, 2qt+2), normalized direct write.
//   qt 8..15 -> part0: k-tiles [0, qt+1) (never masked), raw acc -> Pacc ws;
//               part1: [qt+1, 2qt+2) (diagonal), raw acc -> og.
//   norm_k kernel then does og = (og + Pacc) / (Ls0 + Ls1) on split rows.
// Span drops 32 -> 16 iterations (the R6 critical path was the qt=15 serial
// span at ~2 blocks/CU avg occupancy). Loop body is VERBATIM R6 (verified
// PASS, 47us): same STAGE, V-early-load, QK^T/softmax/PV, barrier.
// ---------------------------------------------------------------------------
__global__ __launch_bounds__(256, 4)
void fa_fwd9(const float* __restrict__ qg, const unsigned short* __restrict__ Ktg,
             const unsigned short* __restrict__ Vtg, float* __restrict__ og,
             float* __restrict__ Pacc, float* __restrict__ Ls0,
             float* __restrict__ Ls1) {
  __shared__ __align__(16) unsigned short Kb[2][4096];
  __shared__ __align__(16) unsigned int Pb[4][16 * 20];  // row stride 20 dw

  const int tid = threadIdx.x;
  const int wave = tid >> 6;
  const int lane = tid & 63;
  const int col = lane & 15;
  const int quad = lane >> 4;

  const int idx = blockIdx.x;             // grid 1536 = 64 bh x 24 jobs
  const int bh = idx & 63;
  const int j = idx >> 6;                 // 0..23
  const int h = bh & 15;
  const int b = bh >> 4;
  const int kvh = h >> 2;
  const int seg = b * SEQ;
  const int tb = (b * NKV + kvh) * 32;

  int qt, k0, k1, mode;                   // mode: 0=full, 1=part0, 2=part1
  if (j < 8) {
    qt = j; k0 = 0; k1 = 2 * (qt + 1); mode = 0;
  } else {
    const int s = j - 8;
    qt = 8 + (s >> 1);
    if ((s & 1) == 0) { k0 = 0;      k1 = qt + 1;       mode = 1; }
    else              { k0 = qt + 1; k1 = 2 * (qt + 1); mode = 2; }
  }
  const int wq0 = qt * 64 + wave * 16;

  // Q A-fragment [m=col][k=quad*8+j], pre-scaled bf16 (scale*log2e folded)
  F8 qf[4];
  {
    const float* qp = qg + ((size_t)(seg + wq0 + col) * NH + h) * HD + quad * 8;
#pragma unroll
    for (int ks = 0; ks < 4; ++ks) {
      floatx4 a = ((const floatx4*)(qp + ks * 32))[0];
      floatx4 c = ((const floatx4*)(qp + ks * 32))[1];
#pragma unroll
      for (int jj = 0; jj < 4; ++jj) {
        qf[ks].u[jj] = f2bf(a[jj] * QSCALE);
        qf[ks].u[4 + jj] = f2bf(c[jj] * QSCALE);
      }
    }
  }

  floatx4 acc[8];
#pragma unroll
  for (int dt = 0; dt < 8; ++dt) acc[dt] = (floatx4){0.f, 0.f, 0.f, 0.f};
  float lsum[4] = {0.f, 0.f, 0.f, 0.f};

  const int stoff = wave * 2048 + lane * 16;

  // Prologue: DMA K tile k0 into buffer 0
  {
    const char* gK = (const char*)Ktg + (size_t)(tb + k0) * 8192 + stoff;
    char* lK = (char*)&Kb[0][0] + wave * 2048;
    glds16(gK, lK);
    glds16(gK + 1024, lK + 1024);
  }
  __syncthreads();

  for (int kt = k0; kt < k1; ++kt) {
    const int cb = (kt - k0) & 1, nb = cb ^ 1;
    const int kbase = kt * 32;
    const bool act = (kbase <= wq0 + 15);

    // ---- (1) V fragments: issue EARLY, global->reg, consumed in PV ----
    F8 vr[8];
    if (act) {
      const unsigned short* Vt = Vtg + (size_t)(tb + kt) * 4096;
#pragma unroll
      for (int dt = 0; dt < 8; ++dt)
        vr[dt].v = *(const short8*)&Vt[((dt * 16 + col) * 4 + (quad ^ (col & 3))) * 8];
    }

    // ---- (2) prefetch next K tile (drained by this iter's barrier) ----
    if (kt + 1 < k1) {
      const char* gK = (const char*)Ktg + (size_t)(tb + kt + 1) * 8192 + stoff;
      char* lK = (char*)&Kb[nb][0] + wave * 2048;
      glds16(gK, lK);
      glds16(gK + 1024, lK + 1024);
    }

    if (act) {
      // ---- QK^T: K B-frags from swizzled LDS tile ----
      floatx4 s0 = {0.f, 0.f, 0.f, 0.f}, s1 = {0.f, 0.f, 0.f, 0.f};
#pragma unroll
      for (int ks = 0; ks < 4; ++ks) {
        F8 kk0, kk1;
        kk0.v = *(const short8*)&Kb[cb][(col * 16 + ((ks * 4 + quad) ^ col)) * 8];
        kk1.v = *(const short8*)&Kb[cb][((16 + col) * 16 + ((ks * 4 + quad) ^ col)) * 8];
        s0 = __builtin_amdgcn_mfma_f32_16x16x32_bf16(qf[ks].v, kk0.v, s0, 0, 0, 0);
        s1 = __builtin_amdgcn_mfma_f32_16x16x32_bf16(qf[ks].v, kk1.v, s1, 0, 0, 0);
      }
      // ---- max-free softmax (exp2; logits pre-scaled by log2e) ----
      const bool diag = (kbase + 31 > wq0);
#pragma unroll
      for (int r = 0; r < 4; ++r) {
        float p0 = __builtin_amdgcn_exp2f(s0[r]);
        float p1 = __builtin_amdgcn_exp2f(s1[r]);
        if (diag) {
          const int q0 = wq0 + quad * 4 + r;
          p0 = (kbase + col > q0) ? 0.f : p0;
          p1 = (kbase + 16 + col > q0) ? 0.f : p1;
        }
        lsum[r] += p0 + p1;
        Pb[wave][(quad * 4 + r) * 20 + col] = pk_bf16(p0, p1);
      }
      // ---- PV: P as A-frag; V from the early-loaded registers ----
      F8 pa;
      pa.v = *(const short8*)&Pb[wave][col * 20 + quad * 4];
#pragma unroll
      for (int dt = 0; dt < 8; ++dt)
        acc[dt] = __builtin_amdgcn_mfma_f32_16x16x32_bf16(pa.v, vr[dt].v, acc[dt], 0, 0, 0);
    }
    __syncthreads();
  }

  // ---- epilogue ----
#pragma unroll
  for (int r = 0; r < 4; ++r) {
    float l = lsum[r];
    l += __shfl_xor(l, 1);
    l += __shfl_xor(l, 2);
    l += __shfl_xor(l, 4);
    l += __shfl_xor(l, 8);
    if (mode == 0) {
      const float inv = 1.0f / l;
      float* op = og + ((size_t)(seg + wq0 + quad * 4 + r) * NH + h) * HD;
#pragma unroll
      for (int dt = 0; dt < 8; ++dt) op[dt * 16 + col] = acc[dt][r] * inv;
    } else {
      const int roff = (qt - 8) * 64 + wave * 16 + quad * 4 + r;
      const int lrow = (b * NH + h) * 512 + roff;
      if (mode == 1) {
        float* pp = Pacc + (size_t)lrow * 128;
#pragma unroll
        for (int dt = 0; dt < 8; ++dt) pp[dt * 16 + col] = acc[dt][r];
        if (col == 0) Ls0[lrow] = l;
      } else {
        float* op = og + ((size_t)(seg + wq0 + quad * 4 + r) * NH + h) * HD;
#pragma unroll
        for (int dt = 0; dt < 8; ++dt) op[dt * 16 + col] = acc[dt][r];
        if (col == 0) Ls1[lrow] = l;
      }
    }
  }
}

// ---------------------------------------------------------------------------
// Combine kernel: og = (og + Pacc) / (Ls0 + Ls1) on the split rows
// (rows 512..1023 of each segment). 4M f32; 8 per thread; grid 2048x256.
// ---------------------------------------------------------------------------
__global__ __launch_bounds__(256)
void norm_k(float* __restrict__ og, const float* __restrict__ Pacc,
            const float* __restrict__ Ls0, const float* __restrict__ Ls1) {
  const int t = blockIdx.x * 256 + threadIdx.x;  // 524288 threads
  const int e = t * 8;                           // element base
  const int lrow = e >> 7;
  const int d = e & 127;
  const float inv = 1.0f / (Ls0[lrow] + Ls1[lrow]);
  const int b = lrow >> 13;
  const int rem = lrow & 8191;
  const int h = rem >> 9;
  const int roff = rem & 511;
  float* op = og + (((size_t)(b * 1024 + 512 + roff) * NH + h) * HD + d);
  const float* pp = Pacc + (size_t)lrow * 128 + d;
#pragma unroll
  for (int i = 0; i < 2; ++i) {
    floatx4 o = ((floatx4*)op)[i];
    floatx4 p = ((const floatx4*)pp)[i];
#pragma unroll
    for (int k = 0; k < 4; ++k) o[k] = (o[k] + p[k]) * inv;
    ((floatx4*)op)[i] = o;
  }
}

// ---------------------------------------------------------------------------
// R6-verified hot kernel (47us PASS): used when ws fits prepass but not the
// split-K partial buffers.
// ---------------------------------------------------------------------------
__global__ __launch_bounds__(256, 4)
void fa_fwd7(const float* __restrict__ qg, const unsigned short* __restrict__ Ktg,
             const unsigned short* __restrict__ Vtg, float* __restrict__ og) {
  __shared__ __align__(16) unsigned short Kb[2][4096];
  __shared__ __align__(16) unsigned int Pb[4][16 * 20];

  const int tid = threadIdx.x;
  const int wave = tid >> 6;
  const int lane = tid & 63;
  const int col = lane & 15;
  const int quad = lane >> 4;

  const int idx = blockIdx.x;
  const int g = idx >> 8;
  const int u = (idx >> 6) & 3;
  const int bh = idx & 63;
  const int qt = g * 4 + ((u + g) & 3);
  const int h = bh & 15;
  const int b = bh >> 4;
  const int kvh = h >> 2;
  const int seg = b * SEQ;
  const int wq0 = qt * 64 + wave * 16;
  const int tb = (b * NKV + kvh) * 32;

  F8 qf[4];
  {
    const float* qp = qg + ((size_t)(seg + wq0 + col) * NH + h) * HD + quad * 8;
#pragma unroll
    for (int ks = 0; ks < 4; ++ks) {
      floatx4 a = ((const floatx4*)(qp + ks * 32))[0];
      floatx4 c = ((const floatx4*)(qp + ks * 32))[1];
#pragma unroll
      for (int jj = 0; jj < 4; ++jj) {
        qf[ks].u[jj] = f2bf(a[jj] * QSCALE);
        qf[ks].u[4 + jj] = f2bf(c[jj] * QSCALE);
      }
    }
  }

  floatx4 acc[8];
#pragma unroll
  for (int dt = 0; dt < 8; ++dt) acc[dt] = (floatx4){0.f, 0.f, 0.f, 0.f};
  float lsum[4] = {0.f, 0.f, 0.f, 0.f};

  const int nkt = 2 * (qt + 1);
  const int stoff = wave * 2048 + lane * 16;

  {
    const char* gK = (const char*)Ktg + (size_t)tb * 8192 + stoff;
    char* lK = (char*)&Kb[0][0] + wave * 2048;
    glds16(gK, lK);
    glds16(gK + 1024, lK + 1024);
  }
  __syncthreads();

  for (int kt = 0; kt < nkt; ++kt) {
    const int cb = kt & 1, nb = cb ^ 1;
    const int kbase = kt * 32;
    const bool act = (kbase <= wq0 + 15);

    F8 vr[8];
    if (act) {
      const unsigned short* Vt = Vtg + (size_t)(tb + kt) * 4096;
#pragma unroll
      for (int dt = 0; dt < 8; ++dt)
        vr[dt].v = *(const short8*)&Vt[((dt * 16 + col) * 4 + (quad ^ (col & 3))) * 8];
    }

    if (kt + 1 < nkt) {
      const char* gK = (const char*)Ktg + (size_t)(tb + kt + 1) * 8192 + stoff;
      char* lK = (char*)&Kb[nb][0] + wave * 2048;
      glds16(gK, lK);
      glds16(gK + 1024, lK + 1024);
    }

    if (act) {
      floatx4 s0 = {0.f, 0.f, 0.f, 0.f}, s1 = {0.f, 0.f, 0.f, 0.f};
#pragma unroll
      for (int ks = 0; ks < 4; ++ks) {
        F8 kk0, kk1;
        kk0.v = *(const short8*)&Kb[cb][(col * 16 + ((ks * 4 + quad) ^ col)) * 8];
        kk1.v = *(const short8*)&Kb[cb][((16 + col) * 16 + ((ks * 4 + quad) ^ col)) * 8];
        s0 = __builtin_amdgcn_mfma_f32_16x16x32_bf16(qf[ks].v, kk0.v, s0, 0, 0, 0);
        s1 = __builtin_amdgcn_mfma_f32_16x16x32_bf16(qf[ks].v, kk1.v, s1, 0, 0, 0);
      }
      const bool diag = (kbase + 31 > wq0);
#pragma unroll
      for (int r = 0; r < 4; ++r) {
        float p0 = __builtin_amdgcn_exp2f(s0[r]);
        float p1 = __builtin_amdgcn_exp2f(s1[r]);
        if (diag) {
          const int q0 = wq0 + quad * 4 + r;
          p0 = (kbase + col > q0) ? 0.f : p0;
          p1 = (kbase + 16 + col > q0) ? 0.f : p1;
        }
        lsum[r] += p0 + p1;
        Pb[wave][(quad * 4 + r) * 20 + col] = pk_bf16(p0, p1);
      }
      F8 pa;
      pa.v = *(const short8*)&Pb[wave][col * 20 + quad * 4];
#pragma unroll
      for (int dt = 0; dt < 8; ++dt)
        acc[dt] = __builtin_amdgcn_mfma_f32_16x16x32_bf16(pa.v, vr[dt].v, acc[dt], 0, 0, 0);
    }
    __syncthreads();
  }

#pragma unroll
  for (int r = 0; r < 4; ++r) {
    float l = lsum[r];
    l += __shfl_xor(l, 1);
    l += __shfl_xor(l, 2);
    l += __shfl_xor(l, 4);
    l += __shfl_xor(l, 8);
    const float inv = 1.0f / l;
    float* op = og + ((size_t)(seg + wq0 + quad * 4 + r) * NH + h) * HD;
#pragma unroll
    for (int dt = 0; dt < 8; ++dt) op[dt * 16 + col] = acc[dt][r] * inv;
  }
}

// ---------------------------------------------------------------------------
// Fallback (R2 kernel) if d_ws is too small for the pre-pass buffers.
// ---------------------------------------------------------------------------
#define KST 136
#define VST 40
#define PST 40

__global__ __launch_bounds__(256, 2)
void fa_fwd(const float* __restrict__ qg, const float* __restrict__ kg,
            const float* __restrict__ vg, float* __restrict__ og) {
  __shared__ unsigned short Klds[32 * KST];
  __shared__ unsigned short Vt[HD * VST];
  __shared__ unsigned short Pl[4][32 * PST];

  const int tid = threadIdx.x;
  const int wave = tid >> 6;
  const int lane = tid & 63;
  const int col = lane & 15;
  const int quad = lane >> 4;

  const int idx = blockIdx.x;
  const int raw = idx & 7;
  const int qt = (idx & 256) ? raw : 7 - raw;
  const int bh = idx >> 3;
  const int h = bh & 15;
  const int b = bh >> 4;
  const int kvh = h >> 2;
  const int seg = b * SEQ;
  const int wq0 = qt * 128 + wave * 32;

  F8 qf[2][4];
#pragma unroll
  for (int mt = 0; mt < 2; ++mt) {
    const size_t qrow = (size_t)(seg + wq0 + mt * 16 + col);
    const float* qp = qg + (qrow * NH + h) * HD + quad * 8;
#pragma unroll
    for (int ks = 0; ks < 4; ++ks) {
      const floatx4* p4 = (const floatx4*)(qp + ks * 32);
      floatx4 a = p4[0], c = p4[1];
#pragma unroll
      for (int jj = 0; jj < 4; ++jj) {
        qf[mt][ks].u[jj] = f2bf(a[jj] * SCALE_F);
        qf[mt][ks].u[4 + jj] = f2bf(c[jj] * SCALE_F);
      }
    }
  }

  floatx4 acc[2][8];
#pragma unroll
  for (int mt = 0; mt < 2; ++mt)
#pragma unroll
    for (int dt = 0; dt < 8; ++dt)
      acc[mt][dt] = (floatx4){0.f, 0.f, 0.f, 0.f};
  float lsum[2][4];
#pragma unroll
  for (int mt = 0; mt < 2; ++mt)
#pragma unroll
    for (int r = 0; r < 4; ++r) lsum[mt][r] = 0.f;

  const int nkt = 4 * (qt + 1);
  const int sr = tid >> 3;
  const int sc = (tid & 7) * 16;

  for (int kt = 0; kt < nkt; ++kt) {
    const int kbase = kt * 32;
    __syncthreads();
    {
      const size_t tok = (size_t)(seg + kbase + sr);
      const floatx4* kp4 = (const floatx4*)(kg + (tok * NKV + kvh) * HD + sc);
      floatx4 kv0 = kp4[0], kv1 = kp4[1], kv2 = kp4[2], kv3 = kp4[3];
      float kf32[16] = {kv0[0],kv0[1],kv0[2],kv0[3], kv1[0],kv1[1],kv1[2],kv1[3],
                        kv2[0],kv2[1],kv2[2],kv2[3], kv3[0],kv3[1],kv3[2],kv3[3]};
      unsigned int* dst = (unsigned int*)&Klds[sr * KST + sc];
#pragma unroll
      for (int jj = 0; jj < 8; ++jj)
        dst[jj] = (unsigned int)f2bf(kf32[2 * jj]) | ((unsigned int)f2bf(kf32[2 * jj + 1]) << 16);
      const floatx4* vp4 = (const floatx4*)(vg + (tok * NKV + kvh) * HD + sc);
      floatx4 vv0 = vp4[0], vv1 = vp4[1], vv2 = vp4[2], vv3 = vp4[3];
      unsigned short vb[16] = {
        f2bf(vv0[0]),f2bf(vv0[1]),f2bf(vv0[2]),f2bf(vv0[3]),
        f2bf(vv1[0]),f2bf(vv1[1]),f2bf(vv1[2]),f2bf(vv1[3]),
        f2bf(vv2[0]),f2bf(vv2[1]),f2bf(vv2[2]),f2bf(vv2[3]),
        f2bf(vv3[0]),f2bf(vv3[1]),f2bf(vv3[2]),f2bf(vv3[3])};
#pragma unroll
      for (int s = 0; s < 16; ++s) {
        int jj = (s + tid) & 15;
        Vt[(sc + jj) * VST + sr] = vb[jj];
      }
    }
    __syncthreads();

    if (kbase > wq0 + 31) continue;

    F8 kf[4][2];
#pragma unroll
    for (int ks = 0; ks < 4; ++ks)
#pragma unroll
      for (int nt = 0; nt < 2; ++nt)
        kf[ks][nt].v = *(const short8*)&Klds[(nt * 16 + col) * KST + ks * 32 + quad * 8];

#pragma unroll
    for (int mt = 0; mt < 2; ++mt) {
      floatx4 s0 = {0.f, 0.f, 0.f, 0.f}, s1 = {0.f, 0.f, 0.f, 0.f};
#pragma unroll
      for (int ks = 0; ks < 4; ++ks) {
        s0 = __builtin_amdgcn_mfma_f32_16x16x32_bf16(qf[mt][ks].v, kf[ks][0].v, s0, 0, 0, 0);
        s1 = __builtin_amdgcn_mfma_f32_16x16x32_bf16(qf[mt][ks].v, kf[ks][1].v, s1, 0, 0, 0);
      }
      const int q0 = wq0 + mt * 16 + quad * 4;
      const bool diag = (kbase + 31 > wq0 + mt * 16);
      unsigned short* pw = &Pl[wave][(mt * 16 + quad * 4) * PST];
#pragma unroll
      for (int r = 0; r < 4; ++r) {
        float p0 = __expf(s0[r]);
        float p1 = __expf(s1[r]);
        if (diag) {
          p0 = (kbase + col > q0 + r) ? 0.f : p0;
          p1 = (kbase + 16 + col > q0 + r) ? 0.f : p1;
        }
        lsum[mt][r] += p0 + p1;
        pw[r * PST + col] = f2bf(p0);
        pw[r * PST + 16 + col] = f2bf(p1);
      }
    }
    F8 pa[2];
#pragma unroll
    for (int mt = 0; mt < 2; ++mt)
      pa[mt].v = *(const short8*)&Pl[wave][(mt * 16 + col) * PST + quad * 8];
#pragma unroll
    for (int dt = 0; dt < 8; ++dt) {
      F8 vb;
      vb.v = *(const short8*)&Vt[(dt * 16 + col) * VST + quad * 8];
#pragma unroll
      for (int mt = 0; mt < 2; ++mt)
        acc[mt][dt] = __builtin_amdgcn_mfma_f32_16x16x32_bf16(pa[mt].v, vb.v, acc[mt][dt], 0, 0, 0);
    }
  }

#pragma unroll
  for (int mt = 0; mt < 2; ++mt) {
#pragma unroll
    for (int r = 0; r < 4; ++r) {
      float l = lsum[mt][r];
      l += __shfl_xor(l, 1);
      l += __shfl_xor(l, 2);
      l += __shfl_xor(l, 4);
      l += __shfl_xor(l, 8);
      const float inv = 1.0f / l;
      const int qi = wq0 + mt * 16 + quad * 4 + r;
      float* op = og + ((size_t)(seg + qi) * NH + h) * HD;
#pragma unroll
      for (int dt = 0; dt < 8; ++dt)
        op[dt * 16 + col] = acc[mt][dt][r] * inv;
    }
  }
}

extern "C" void kernel_launch(void* const* d_in, const int* in_sizes, int n_in,
                              void* d_out, int out_size, void* d_ws, size_t ws_size,
                              hipStream_t stream) {
  const float* q = (const float*)d_in[0];
  const float* k = (const float*)d_in[1];
  const float* v = (const float*)d_in[2];
  float* out = (float*)d_out;
  const size_t MB = 1024 * 1024;
  if (ws_size >= 26 * MB) {
    // split-K path: Ktg 4MB | Vtg 4MB | Pacc 16MB | Ls0 128KB | Ls1 128KB
    unsigned short* Ktg = (unsigned short*)d_ws;
    unsigned short* Vtg = Ktg + 2097152;
    float* Pacc = (float*)((char*)d_ws + 8 * MB);
    float* Ls0 = (float*)((char*)d_ws + 24 * MB);
    float* Ls1 = Ls0 + 32768;
    hipLaunchKernelGGL(prepass, dim3(1024), dim3(256), 0, stream, k, v, Ktg, Vtg);
    hipLaunchKernelGGL(fa_fwd9, dim3(1536), dim3(256), 0, stream, q, Ktg, Vtg,
                       out, Pacc, Ls0, Ls1);
    hipLaunchKernelGGL(norm_k, dim3(2048), dim3(256), 0, stream, out, Pacc, Ls0, Ls1);
  } else if (ws_size >= 8 * MB) {
    unsigned short* Ktg = (unsigned short*)d_ws;
    unsigned short* Vtg = Ktg + 2097152;
    hipLaunchKernelGGL(prepass, dim3(1024), dim3(256), 0, stream, k, v, Ktg, Vtg);
    hipLaunchKernelGGL(fa_fwd7, dim3(1024), dim3(256), 0, stream, q, Ktg, Vtg, out);
  } else {
    hipLaunchKernelGGL(fa_fwd, dim3(512), dim3(256), 0, stream, q, k, v, out);
  }
}